// Round 22
// baseline (146.897 us; speedup 1.0000x reference)
//
#include <hip/hip_runtime.h>
#include <hip/hip_fp16.h>
#include <math.h>

#define H 6
#define D 128
#define K_ALL (H * D)   // 768
#define TSTEPS 24       // K_ALL / 32
#define PADK 776        // 768 + 8 halves pad
#define NPB 8           // nodes per block (2 waves per node, 16 waves)
#define BSTRIDE 128     // fixed col-bucket capacity per node

typedef _Float16 f16x8 __attribute__((ext_vector_type(8)));
typedef float f32x4 __attribute__((ext_vector_type(4)));

struct FoldArgs {
    const float* W[4];
    const float* as[4];
    const float* ad[4];
};

// ---------------- K1: zero deg + wa_all dots ----------------

__global__ __launch_bounds__(256) void zero_wa_kernel(int4* __restrict__ degz, int n4,
                                                      int zBlocks, FoldArgs fa,
                                                      float* __restrict__ wa_all) {
    int b = blockIdx.x;
    int tid = threadIdx.x;
    if (b < zBlocks) {
        int i = b * 256 + tid;
        if (i < n4) degz[i] = make_int4(0, 0, 0, 0);
        return;
    }
    int t = (b - zBlocks) * 256 + tid;   // < 6144
    if (t >= 4 * 1536) return;
    int l = t / 1536;
    int r = t % 1536;
    int k = r / 12, j = r % 12;
    int h = (j < 6) ? j : (j - 6);
    const float* att = (j < 6) ? fa.as[l] : fa.ad[l];
    const float* wrow = fa.W[l] + (size_t)k * K_ALL + h * D;
    const float* arow = att + h * D;
    float s = 0.f;
    #pragma unroll 8
    for (int c = 0; c < D; c++) s += wrow[c] * arow[c];
    wa_all[(size_t)l * 1536 + k * 12 + j] = s;
}

// ---------------- K2: scatter-hist | bf pack | waf pack | layer-0 a ----------------
// a0-MFMA blocks build L0 B-fragments inline from wa_all (K1 -> safe); they
// must NOT read waf (packed by other blocks of THIS dispatch — r16 race).

__global__ __launch_bounds__(256) void prep2_kernel(const int* __restrict__ src,
                                                    const int* __restrict__ dst,
                                                    int* __restrict__ deg,
                                                    int* __restrict__ col, int E,
                                                    int scatBlocks, FoldArgs fa,
                                                    const float* __restrict__ wa_all,
                                                    _Float16* __restrict__ waf,
                                                    _Float16* __restrict__ bf,
                                                    const float* __restrict__ x_in,
                                                    float* __restrict__ a0, int N) {
    __shared__ _Float16 xs[16][136];
    int b = blockIdx.x;
    int tid = threadIdx.x;
    if (b < scatBlocks) {
        int e = b * 256 + tid;
        if (e < E) {
            int n = dst[e];
            int p = atomicAdd(&deg[n], 1);
            if (p < BSTRIDE) col[(size_t)n * BSTRIDE + p] = src[e];
        }
        return;
    }
    int bb = b - scatBlocks;
    if (bb < 192) {
        int idx = bb * 256 + tid;    // < 49152
        int l63 = idx & 63;
        int ct = (idx >> 6) & 7;
        int t = (idx >> 9) % TSTEPS;
        int layer = idx / (TSTEPS * 8 * 64);
        const float* W = fa.W[layer];
        int c = ct * 16 + (l63 & 15);
        f16x8 v;
        #pragma unroll
        for (int j = 0; j < 8; j++) {
            int k = t * 32 + ((l63 >> 4) << 3) + j;
            v[j] = (_Float16)W[(size_t)(k & 127) * K_ALL + ((k >> 7) << 7) + c];
        }
        *(f16x8*)(bf + ((size_t)idx << 3)) = v;
        return;
    }
    bb -= 192;
    if (bb < 4) {
        int L = bb;
        int lane = tid & 63;
        int t = tid >> 6;
        int j = lane & 15;
        const float* wl = wa_all + (size_t)L * 1536;
        f16x8 vv;
        #pragma unroll
        for (int jj = 0; jj < 8; jj++) {
            int k = t * 32 + ((lane >> 4) << 3) + jj;
            float sv = (j < 12) ? wl[k * 12 + j] : 0.f;
            vv[jj] = (_Float16)sv;
        }
        *(f16x8*)(waf + (size_t)L * 2048 + (size_t)t * 512 + (size_t)lane * 8) = vv;
        return;
    }
    bb -= 4;
    // layer-0 a via MFMA: 16 nodes per block
    int base_node = bb << 4;
    {
        int row = tid >> 4;
        int coff = (tid & 15) * 8;
        int node = base_node + row;
        f16x8 v = {};
        if (node < N) {
            const float* sp = x_in + (size_t)node * D + coff;
            float4 u0 = *(const float4*)sp;
            float4 u1 = *(const float4*)(sp + 4);
            v[0] = (_Float16)u0.x; v[1] = (_Float16)u0.y;
            v[2] = (_Float16)u0.z; v[3] = (_Float16)u0.w;
            v[4] = (_Float16)u1.x; v[5] = (_Float16)u1.y;
            v[6] = (_Float16)u1.z; v[7] = (_Float16)u1.w;
        }
        *(f16x8*)&xs[row][coff] = v;
    }
    __syncthreads();
    if (tid < 64) {
        int lane = tid;
        int cl = lane & 15;
        int r0 = (lane >> 4) << 2;
        const float* wl0 = wa_all;
        f32x4 ac = {0.f, 0.f, 0.f, 0.f};
        #pragma unroll
        for (int t = 0; t < 4; t++) {
            f16x8 av = *(const f16x8*)&xs[cl][t * 32 + ((lane >> 4) << 3)];
            f16x8 bv;
            #pragma unroll
            for (int jj = 0; jj < 8; jj++) {
                int k = t * 32 + ((lane >> 4) << 3) + jj;
                float sv = (cl < 12) ? wl0[k * 12 + cl] : 0.f;
                bv[jj] = (_Float16)sv;
            }
            ac = __builtin_amdgcn_mfma_f32_16x16x32_f16(av, bv, ac, 0, 0, 0);
        }
        if (cl < 12) {
            #pragma unroll
            for (int reg = 0; reg < 4; reg++) {
                int node = base_node + r0 + reg;
                if (node < N) a0[(size_t)node * 12 + cl] = ac[reg];
            }
        }
    }
}

__device__ __forceinline__ float rlf(float v, int j) {
    return __int_as_float(__builtin_amdgcn_readlane(__float_as_int(v), j));
}

// 18 partial sums per (node, half): unnormalized acc + denominators.
struct AggPart {
    float a00, a01, a02, a03, a04, a05;
    float a10, a11, a12, a13, a14, a15;
    float d0, d1, d2, d3, d4, d5;
};

// one HALF of node n's entries (half 0: [0,nA), half 1: [nA,nent)).
// r14 no-reduction softmax + r18 prefetch + r20 unconditional col read.
__device__ __forceinline__ void aggregate_half(const float* __restrict__ x,
                                               const float* __restrict__ a,
                                               const int* __restrict__ deg_,
                                               const int* __restrict__ col,
                                               int n, int lane, int half, int Nn,
                                               AggPart& P) {
    const int deg = deg_[n];
    const int start = n << 7;   // BSTRIDE = 128
    const int nent = deg + 1;

    if (nent <= 128) {
        const int nA = (nent + 1) >> 1;      // <= 64
        const int base = half ? nA : 0;
        const int cnt = half ? (nent - nA) : nA;
        if (cnt <= 0) return;                // P stays zero
        const int idxL = base + lane;        // < 128 always
        int colv = col[start + idxL];        // parallel with deg load
        int sc = ((unsigned)colv < (unsigned)Nn) ? colv : n;
        int s = (idxL < deg) ? sc : n;       // entry 'deg' = self loop

        const float* xb = x + (lane << 1);   // channels 2*lane, 2*lane+1
        float2 cur0, cur1, nxt0, nxt1;
        {
            int t0 = __builtin_amdgcn_readlane(s, 0);
            cur0 = *(const float2*)(xb + (size_t)t0 * D);
        }
        cur1 = make_float2(0.f, 0.f);
        nxt0 = make_float2(0.f, 0.f);
        nxt1 = make_float2(0.f, 0.f);
        if (cnt > 1) {
            int t1 = __builtin_amdgcn_readlane(s, 1);
            cur1 = *(const float2*)(xb + (size_t)t1 * D);
        }
        if (cnt > 2) {
            int t2 = __builtin_amdgcn_readlane(s, 2);
            nxt0 = *(const float2*)(xb + (size_t)t2 * D);
        }
        if (cnt > 3) {
            int t3 = __builtin_amdgcn_readlane(s, 3);
            nxt1 = *(const float2*)(xb + (size_t)t3 * D);
        }

        float adst[H];
        #pragma unroll
        for (int h = 0; h < H; h++) adst[h] = a[(size_t)n * 12 + 6 + h];
        const float* as_ = a + (size_t)s * 12;
        float4 v0 = *(const float4*)as_;
        float2 v1 = *(const float2*)(as_ + 4);
        float e0 = v0.x + adst[0], e1 = v0.y + adst[1], e2 = v0.z + adst[2];
        float e3 = v0.w + adst[3], e4 = v1.x + adst[4], e5 = v1.y + adst[5];
        e0 = e0 > 0.f ? e0 : 0.2f * e0;  e1 = e1 > 0.f ? e1 : 0.2f * e1;
        e2 = e2 > 0.f ? e2 : 0.2f * e2;  e3 = e3 > 0.f ? e3 : 0.2f * e3;
        e4 = e4 > 0.f ? e4 : 0.2f * e4;  e5 = e5 > 0.f ? e5 : 0.2f * e5;
        float w0 = __expf(e0), w1 = __expf(e1), w2 = __expf(e2);
        float w3 = __expf(e3), w4 = __expf(e4), w5 = __expf(e5);

        for (int j = 0; j < cnt; j += 2) {
            float2 fut0 = make_float2(0.f, 0.f), fut1 = make_float2(0.f, 0.f);
            if (j + 4 < cnt) {
                int t = __builtin_amdgcn_readlane(s, j + 4);
                fut0 = *(const float2*)(xb + (size_t)t * D);
            }
            if (j + 5 < cnt) {
                int t = __builtin_amdgcn_readlane(s, j + 5);
                fut1 = *(const float2*)(xb + (size_t)t * D);
            }
            {
                float b0 = rlf(w0, j), b1 = rlf(w1, j), b2 = rlf(w2, j);
                float b3 = rlf(w3, j), b4 = rlf(w4, j), b5 = rlf(w5, j);
                P.d0 += b0; P.d1 += b1; P.d2 += b2; P.d3 += b3; P.d4 += b4; P.d5 += b5;
                P.a00 += b0 * cur0.x; P.a10 += b0 * cur0.y;
                P.a01 += b1 * cur0.x; P.a11 += b1 * cur0.y;
                P.a02 += b2 * cur0.x; P.a12 += b2 * cur0.y;
                P.a03 += b3 * cur0.x; P.a13 += b3 * cur0.y;
                P.a04 += b4 * cur0.x; P.a14 += b4 * cur0.y;
                P.a05 += b5 * cur0.x; P.a15 += b5 * cur0.y;
            }
            if (j + 1 < cnt) {
                float b0 = rlf(w0, j + 1), b1 = rlf(w1, j + 1), b2 = rlf(w2, j + 1);
                float b3 = rlf(w3, j + 1), b4 = rlf(w4, j + 1), b5 = rlf(w5, j + 1);
                P.d0 += b0; P.d1 += b1; P.d2 += b2; P.d3 += b3; P.d4 += b4; P.d5 += b5;
                P.a00 += b0 * cur1.x; P.a10 += b0 * cur1.y;
                P.a01 += b1 * cur1.x; P.a11 += b1 * cur1.y;
                P.a02 += b2 * cur1.x; P.a12 += b2 * cur1.y;
                P.a03 += b3 * cur1.x; P.a13 += b3 * cur1.y;
                P.a04 += b4 * cur1.x; P.a14 += b4 * cur1.y;
                P.a05 += b5 * cur1.x; P.a15 += b5 * cur1.y;
            }
            cur0 = nxt0; cur1 = nxt1;
            nxt0 = fut0; nxt1 = fut1;
        }
    } else {
        // pathological fallback: half 0 does the whole node serially (cap BSTRIDE)
        if (half) return;
        float adst[H];
        #pragma unroll
        for (int h = 0; h < H; h++) adst[h] = a[(size_t)n * 12 + 6 + h];
        int dl = deg < BSTRIDE ? deg : BSTRIDE;
        const float* xb = x + (lane << 1);
        for (int j = 0; j <= dl; j++) {
            int s = (j < dl) ? col[start + j] : n;
            float w[H];
            #pragma unroll
            for (int h = 0; h < H; h++) {
                float e = a[(size_t)s * 12 + h] + adst[h];
                e = (e > 0.f) ? e : 0.2f * e;
                w[h] = __expf(e);
            }
            float2 xv = *(const float2*)(xb + (size_t)s * D);
            P.d0 += w[0]; P.d1 += w[1]; P.d2 += w[2];
            P.d3 += w[3]; P.d4 += w[4]; P.d5 += w[5];
            P.a00 += w[0] * xv.x; P.a10 += w[0] * xv.y;
            P.a01 += w[1] * xv.x; P.a11 += w[1] * xv.y;
            P.a02 += w[2] * xv.x; P.a12 += w[2] * xv.y;
            P.a03 += w[3] * xv.x; P.a13 += w[3] * xv.y;
            P.a04 += w[4] * xv.x; P.a14 += w[4] * xv.y;
            P.a05 += w[5] * xv.x; P.a15 += w[5] * xv.y;
        }
    }
}

// ---------------- fused layer: 2-wave-per-node aggregate + MFMA GEMM + a ----------------
// 1024 threads = 16 waves. Wave w (w<8): half 0 of node m0+w; wave w+8: half 1.
// Half-1 waves deposit partials in LDS; half-0 combines, normalizes, writes
// the f16 row; GEMM/epilogue identical to the proven r20 form (waves 0..7).
__global__ __launch_bounds__(1024) void layer_kernel(const float* __restrict__ x,
                                                     const float* __restrict__ a_in,
                                                     const int* __restrict__ deg_,
                                                     const int* __restrict__ col,
                                                     const _Float16* __restrict__ bf,
                                                     const float* __restrict__ bias,
                                                     float* __restrict__ xout,
                                                     const _Float16* __restrict__ awf,
                                                     float* __restrict__ a_out, int M) {
    __shared__ _Float16 xs16[16][PADK];   // rows 0..7 real; 8..15 garbage
    __shared__ _Float16 xso[16][136];
    __shared__ float pB[8][64][12];       // half-1 partial accs
    __shared__ float dB[8][8];            // half-1 partial denominators
    const int wave = (int)(threadIdx.x >> 6);
    const int lane = (int)(threadIdx.x & 63);
    const int nl = wave & 7;              // node slot
    const int half = wave >> 3;
    const int m0 = (int)(blockIdx.x << 3);
    const int n = m0 + nl;

    // phase 1: both halves aggregate in parallel
    AggPart P = {};
    if (n < M) aggregate_half(x, a_in, deg_, col, n, lane, half, M, P);

    if (half == 1 && n < M) {
        float* pp = &pB[nl][lane][0];
        pp[0] = P.a00;  pp[1] = P.a01;  pp[2] = P.a02;
        pp[3] = P.a03;  pp[4] = P.a04;  pp[5] = P.a05;
        pp[6] = P.a10;  pp[7] = P.a11;  pp[8] = P.a12;
        pp[9] = P.a13;  pp[10] = P.a14; pp[11] = P.a15;
        if (lane == 0) {
            dB[nl][0] = P.d0; dB[nl][1] = P.d1; dB[nl][2] = P.d2;
            dB[nl][3] = P.d3; dB[nl][4] = P.d4; dB[nl][5] = P.d5;
        }
    }
    __syncthreads();

    if (half == 0 && n < M) {
        const float* pp = &pB[nl][lane][0];
        float a00 = P.a00 + pp[0], a01 = P.a01 + pp[1], a02 = P.a02 + pp[2];
        float a03 = P.a03 + pp[3], a04 = P.a04 + pp[4], a05 = P.a05 + pp[5];
        float a10 = P.a10 + pp[6], a11 = P.a11 + pp[7], a12 = P.a12 + pp[8];
        float a13 = P.a13 + pp[9], a14 = P.a14 + pp[10], a15 = P.a15 + pp[11];
        float i0 = 1.f / (P.d0 + dB[nl][0]);
        float i1 = 1.f / (P.d1 + dB[nl][1]);
        float i2 = 1.f / (P.d2 + dB[nl][2]);
        float i3 = 1.f / (P.d3 + dB[nl][3]);
        float i4 = 1.f / (P.d4 + dB[nl][4]);
        float i5 = 1.f / (P.d5 + dB[nl][5]);
        _Float16* xsrow = &xs16[nl][0];
        int c = lane << 1;
        xsrow[0 * D + c] = (_Float16)(a00 * i0);  xsrow[0 * D + c + 1] = (_Float16)(a10 * i0);
        xsrow[1 * D + c] = (_Float16)(a01 * i1);  xsrow[1 * D + c + 1] = (_Float16)(a11 * i1);
        xsrow[2 * D + c] = (_Float16)(a02 * i2);  xsrow[2 * D + c + 1] = (_Float16)(a12 * i2);
        xsrow[3 * D + c] = (_Float16)(a03 * i3);  xsrow[3 * D + c + 1] = (_Float16)(a13 * i3);
        xsrow[4 * D + c] = (_Float16)(a04 * i4);  xsrow[4 * D + c + 1] = (_Float16)(a14 * i4);
        xsrow[5 * D + c] = (_Float16)(a05 * i5);  xsrow[5 * D + c + 1] = (_Float16)(a15 * i5);
    }
    __syncthreads();

    // phase 2: GEMM by waves 0..7 (r20-proven form)
    if (half == 0) {
        f32x4 acc = {0.f, 0.f, 0.f, 0.f};
        const _Float16* ars = &xs16[lane & 15][(lane >> 4) << 3];
        const _Float16* bp = bf + (size_t)nl * 512 + (size_t)lane * 8;
        for (int t = 0; t < TSTEPS; t++) {
            f16x8 av = *(const f16x8*)(ars + t * 32);
            f16x8 bv = *(const f16x8*)(bp + (size_t)t * 4096);
            acc = __builtin_amdgcn_mfma_f32_16x16x32_f16(av, bv, acc, 0, 0, 0);
        }

        const float inv6 = 1.0f / 6.0f;
        const int cl = lane & 15;
        const int ccol = nl * 16 + cl;
        const int r0 = (lane >> 4) << 2;
        const float bs = bias[ccol];
        #pragma unroll
        for (int reg = 0; reg < 4; reg++) {
            int ml = r0 + reg;
            int m = m0 + ml;
            float v = acc[reg] * inv6 + bs;
            v = v > 0.f ? v : 0.f;
            if (ml < NPB && m < M) xout[(size_t)m * D + ccol] = v;
            xso[ml][ccol] = (_Float16)v;
        }
    }

    // phase 3: fused next-layer attention logits (wave 0)
    if (awf) {
        __syncthreads();
        if (wave == 0) {
            const int cl = lane & 15;
            const int r0 = (lane >> 4) << 2;
            f32x4 ac = {0.f, 0.f, 0.f, 0.f};
            #pragma unroll
            for (int t = 0; t < 4; t++) {
                f16x8 av = *(const f16x8*)&xso[cl][t * 32 + ((lane >> 4) << 3)];
                f16x8 bv = *(const f16x8*)(awf + (size_t)t * 512 + (size_t)lane * 8);
                ac = __builtin_amdgcn_mfma_f32_16x16x32_f16(av, bv, ac, 0, 0, 0);
            }
            if (cl < 12) {
                #pragma unroll
                for (int reg = 0; reg < 4; reg++) {
                    int ml = r0 + reg;
                    int m = m0 + ml;
                    if (ml < NPB && m < M) a_out[(size_t)m * 12 + cl] = ac[reg];
                }
            }
        }
    }
}

// ---------------- host ----------------

extern "C" void kernel_launch(void* const* d_in, const int* in_sizes, int n_in,
                              void* d_out, int out_size, void* d_ws, size_t ws_size,
                              hipStream_t stream) {
    const float* x_in = (const float*)d_in[0];
    const int* ei = (const int*)d_in[1];
    int N = in_sizes[0] / D;
    int E = in_sizes[1] / 2;
    const int* srcp = ei;
    const int* dstp = ei + E;

    size_t bf_halves_per_layer = (size_t)TSTEPS * 8 * 512;   // 98304

    float* ws = (float*)d_ws;
    float* bufA = ws;
    float* bufB = bufA + (size_t)N * D;
    float* abuf0 = bufB + (size_t)N * D;
    float* abuf1 = abuf0 + (size_t)N * 12;
    float* wa_all = abuf1 + (size_t)N * 12;          // 4*1536 floats
    _Float16* waf = (_Float16*)(wa_all + 4 * 1536);  // 4 layers x 2048 halves
    _Float16* w16f = waf + 4 * 2048;
    int* deg = (int*)(w16f + 4 * bf_halves_per_layer);
    int* col = deg + N;                               // N * BSTRIDE ints

    FoldArgs fa;
    for (int l = 0; l < 4; l++) {
        fa.W[l]  = (const float*)d_in[2 + 4 * l];
        fa.as[l] = (const float*)d_in[3 + 4 * l];
        fa.ad[l] = (const float*)d_in[4 + 4 * l];
    }

    // K1: zero deg + wa_all dots
    int n4 = (N + 3) / 4;
    int zBlocks = (n4 + 255) / 256;
    zero_wa_kernel<<<zBlocks + 24, 256, 0, stream>>>((int4*)deg, n4, zBlocks, fa, wa_all);

    // K2: scatter-hist | bf pack | waf pack | layer-0 a
    int scatBlocks = (E + 255) / 256;
    int a0Blocks = (N + 15) / 16;
    prep2_kernel<<<scatBlocks + 192 + 4 + a0Blocks, 256, 0, stream>>>(
        srcp, dstp, deg, col, E, scatBlocks, fa, wa_all, waf, w16f, x_in, abuf0, N);

    const float* xcur = x_in;
    float* acur = abuf0;
    float* anext = abuf1;
    for (int l = 0; l < 4; l++) {
        const float* b = (const float*)d_in[5 + 4 * l];
        float* xout = (l == 3) ? (float*)d_out : ((l & 1) ? bufB : bufA);
        const _Float16* awf = (l < 3) ? (waf + (size_t)(l + 1) * 2048) : (const _Float16*)nullptr;

        layer_kernel<<<(N + NPB - 1) / NPB, 1024, 0, stream>>>(xcur, acur, deg, col,
                                                               w16f + (size_t)l * bf_halves_per_layer,
                                                               b, xout, awf, anext, N);
        xcur = xout;
        float* tmp = acur; acur = anext; anext = tmp;
    }
}

// Round 23
// 131.285 us; speedup vs baseline: 1.1189x; 1.1189x over previous
//
#include <hip/hip_runtime.h>
#include <hip/hip_fp16.h>
#include <math.h>

#define H 6
#define D 128
#define K_ALL (H * D)   // 768
#define TSTEPS 24       // K_ALL / 32
#define PADK 776        // 768 + 8 halves pad -> conflict-free fragment reads
#define NPB 8           // nodes per block (1 per wave)
#define BSTRIDE 128     // fixed col-bucket capacity per node

typedef _Float16 f16x8 __attribute__((ext_vector_type(8)));
typedef float f32x4 __attribute__((ext_vector_type(4)));

struct FoldArgs {
    const float* W[4];
    const float* as[4];
    const float* ad[4];
};

// ---------------- K1: zero deg + wa_all dots ----------------

__global__ __launch_bounds__(256) void zero_wa_kernel(int4* __restrict__ degz, int n4,
                                                      int zBlocks, FoldArgs fa,
                                                      float* __restrict__ wa_all) {
    int b = blockIdx.x;
    int tid = threadIdx.x;
    if (b < zBlocks) {
        int i = b * 256 + tid;
        if (i < n4) degz[i] = make_int4(0, 0, 0, 0);
        return;
    }
    int t = (b - zBlocks) * 256 + tid;   // < 6144
    if (t >= 4 * 1536) return;
    int l = t / 1536;
    int r = t % 1536;
    int k = r / 12, j = r % 12;
    int h = (j < 6) ? j : (j - 6);
    const float* att = (j < 6) ? fa.as[l] : fa.ad[l];
    const float* wrow = fa.W[l] + (size_t)k * K_ALL + h * D;
    const float* arow = att + h * D;
    float s = 0.f;
    #pragma unroll 8
    for (int c = 0; c < D; c++) s += wrow[c] * arow[c];
    wa_all[(size_t)l * 1536 + k * 12 + j] = s;
}

// ---------------- K2: scatter-hist | bf pack | waf pack | layer-0 a ----------------
// a0-MFMA blocks build their L0 B-fragments inline from wa_all (K1 -> safe);
// they must NOT read waf (packed by other blocks of THIS dispatch — r16 race).

__global__ __launch_bounds__(256) void prep2_kernel(const int* __restrict__ src,
                                                    const int* __restrict__ dst,
                                                    int* __restrict__ deg,
                                                    int* __restrict__ col, int E,
                                                    int scatBlocks, FoldArgs fa,
                                                    const float* __restrict__ wa_all,
                                                    _Float16* __restrict__ waf,
                                                    _Float16* __restrict__ bf,
                                                    const float* __restrict__ x_in,
                                                    float* __restrict__ a0, int N) {
    __shared__ _Float16 xs[16][136];
    int b = blockIdx.x;
    int tid = threadIdx.x;
    if (b < scatBlocks) {
        int e = b * 256 + tid;
        if (e < E) {
            int n = dst[e];
            int p = atomicAdd(&deg[n], 1);
            if (p < BSTRIDE) col[(size_t)n * BSTRIDE + p] = src[e];
        }
        return;
    }
    int bb = b - scatBlocks;
    if (bb < 192) {
        int idx = bb * 256 + tid;    // < 49152
        int l63 = idx & 63;
        int ct = (idx >> 6) & 7;
        int t = (idx >> 9) % TSTEPS;
        int layer = idx / (TSTEPS * 8 * 64);
        const float* W = fa.W[layer];
        int c = ct * 16 + (l63 & 15);
        f16x8 v;
        #pragma unroll
        for (int j = 0; j < 8; j++) {
            int k = t * 32 + ((l63 >> 4) << 3) + j;
            v[j] = (_Float16)W[(size_t)(k & 127) * K_ALL + ((k >> 7) << 7) + c];
        }
        *(f16x8*)(bf + ((size_t)idx << 3)) = v;
        return;
    }
    bb -= 192;
    if (bb < 4) {
        int L = bb;
        int lane = tid & 63;
        int t = tid >> 6;
        int j = lane & 15;
        const float* wl = wa_all + (size_t)L * 1536;
        f16x8 vv;
        #pragma unroll
        for (int jj = 0; jj < 8; jj++) {
            int k = t * 32 + ((lane >> 4) << 3) + jj;
            float sv = (j < 12) ? wl[k * 12 + j] : 0.f;
            vv[jj] = (_Float16)sv;
        }
        *(f16x8*)(waf + (size_t)L * 2048 + (size_t)t * 512 + (size_t)lane * 8) = vv;
        return;
    }
    bb -= 4;
    // layer-0 a via MFMA: 16 nodes per block
    int base_node = bb << 4;
    {
        int row = tid >> 4;
        int coff = (tid & 15) * 8;
        int node = base_node + row;
        f16x8 v = {};
        if (node < N) {
            const float* sp = x_in + (size_t)node * D + coff;
            float4 u0 = *(const float4*)sp;
            float4 u1 = *(const float4*)(sp + 4);
            v[0] = (_Float16)u0.x; v[1] = (_Float16)u0.y;
            v[2] = (_Float16)u0.z; v[3] = (_Float16)u0.w;
            v[4] = (_Float16)u1.x; v[5] = (_Float16)u1.y;
            v[6] = (_Float16)u1.z; v[7] = (_Float16)u1.w;
        }
        *(f16x8*)&xs[row][coff] = v;
    }
    __syncthreads();
    if (tid < 64) {
        int lane = tid;
        int cl = lane & 15;
        int r0 = (lane >> 4) << 2;
        const float* wl0 = wa_all;
        f32x4 ac = {0.f, 0.f, 0.f, 0.f};
        #pragma unroll
        for (int t = 0; t < 4; t++) {
            f16x8 av = *(const f16x8*)&xs[cl][t * 32 + ((lane >> 4) << 3)];
            f16x8 bv;
            #pragma unroll
            for (int jj = 0; jj < 8; jj++) {
                int k = t * 32 + ((lane >> 4) << 3) + jj;
                float sv = (cl < 12) ? wl0[k * 12 + cl] : 0.f;
                bv[jj] = (_Float16)sv;
            }
            ac = __builtin_amdgcn_mfma_f32_16x16x32_f16(av, bv, ac, 0, 0, 0);
        }
        if (cl < 12) {
            #pragma unroll
            for (int reg = 0; reg < 4; reg++) {
                int node = base_node + r0 + reg;
                if (node < N) a0[(size_t)node * 12 + cl] = ac[reg];
            }
        }
    }
}

__device__ __forceinline__ float rlf(float v, int j) {
    return __int_as_float(__builtin_amdgcn_readlane(__float_as_int(v), j));
}

// per-wave aggregate: r14 (no cross-lane reductions) + r18 (3-pair prefetch)
// + r20 (unconditional col read -> deg/col loads issue in parallel).
__device__ __forceinline__ void aggregate_node(const float* __restrict__ x,
                                               const float* __restrict__ a,
                                               const int* __restrict__ deg_,
                                               const int* __restrict__ col,
                                               int n, int lane, int Nn,
                                               _Float16* __restrict__ xsrow) {
    const int deg = deg_[n];
    const int start = n << 7;   // BSTRIDE = 128
    int colv = col[start + lane];          // independent of deg load
    const int nent = deg + 1;

    if (nent <= 64) {
        int sc = ((unsigned)colv < (unsigned)Nn) ? colv : n;  // sanitize garbage
        int s = (lane < deg) ? sc : n;      // lane 'deg' = self loop

        // ---- x prefetch head: depends only on s ----
        const float* xb = x + (lane << 1);
        float2 cur0, cur1, nxt0, nxt1;
        {
            int t0 = __builtin_amdgcn_readlane(s, 0);
            cur0 = *(const float2*)(xb + (size_t)t0 * D);
        }
        cur1 = make_float2(0.f, 0.f);
        nxt0 = make_float2(0.f, 0.f);
        nxt1 = make_float2(0.f, 0.f);
        if (nent > 1) {
            int t1 = __builtin_amdgcn_readlane(s, 1);
            cur1 = *(const float2*)(xb + (size_t)t1 * D);
        }
        if (nent > 2) {
            int t2 = __builtin_amdgcn_readlane(s, 2);
            nxt0 = *(const float2*)(xb + (size_t)t2 * D);
        }
        if (nent > 3) {
            int t3 = __builtin_amdgcn_readlane(s, 3);
            nxt1 = *(const float2*)(xb + (size_t)t3 * D);
        }

        // ---- logits + exp (overlaps prefetch latency) ----
        float adst[H];
        #pragma unroll
        for (int h = 0; h < H; h++) adst[h] = a[(size_t)n * 12 + 6 + h];
        const float* as_ = a + (size_t)s * 12;
        float4 v0 = *(const float4*)as_;
        float2 v1 = *(const float2*)(as_ + 4);
        float e0 = v0.x + adst[0], e1 = v0.y + adst[1], e2 = v0.z + adst[2];
        float e3 = v0.w + adst[3], e4 = v1.x + adst[4], e5 = v1.y + adst[5];
        e0 = e0 > 0.f ? e0 : 0.2f * e0;  e1 = e1 > 0.f ? e1 : 0.2f * e1;
        e2 = e2 > 0.f ? e2 : 0.2f * e2;  e3 = e3 > 0.f ? e3 : 0.2f * e3;
        e4 = e4 > 0.f ? e4 : 0.2f * e4;  e5 = e5 > 0.f ? e5 : 0.2f * e5;
        float w0 = __expf(e0), w1 = __expf(e1), w2 = __expf(e2);
        float w3 = __expf(e3), w4 = __expf(e4), w5 = __expf(e5);

        float d0 = 0, d1 = 0, d2 = 0, d3 = 0, d4 = 0, d5 = 0;
        float a00 = 0, a01 = 0, a02 = 0, a03 = 0, a04 = 0, a05 = 0;
        float a10 = 0, a11 = 0, a12 = 0, a13 = 0, a14 = 0, a15 = 0;

        for (int j = 0; j < nent; j += 2) {
            float2 fut0 = make_float2(0.f, 0.f), fut1 = make_float2(0.f, 0.f);
            if (j + 4 < nent) {
                int t = __builtin_amdgcn_readlane(s, j + 4);
                fut0 = *(const float2*)(xb + (size_t)t * D);
            }
            if (j + 5 < nent) {
                int t = __builtin_amdgcn_readlane(s, j + 5);
                fut1 = *(const float2*)(xb + (size_t)t * D);
            }
            {
                float b0 = rlf(w0, j), b1 = rlf(w1, j), b2 = rlf(w2, j);
                float b3 = rlf(w3, j), b4 = rlf(w4, j), b5 = rlf(w5, j);
                d0 += b0; d1 += b1; d2 += b2; d3 += b3; d4 += b4; d5 += b5;
                a00 += b0 * cur0.x; a10 += b0 * cur0.y;
                a01 += b1 * cur0.x; a11 += b1 * cur0.y;
                a02 += b2 * cur0.x; a12 += b2 * cur0.y;
                a03 += b3 * cur0.x; a13 += b3 * cur0.y;
                a04 += b4 * cur0.x; a14 += b4 * cur0.y;
                a05 += b5 * cur0.x; a15 += b5 * cur0.y;
            }
            if (j + 1 < nent) {
                float b0 = rlf(w0, j + 1), b1 = rlf(w1, j + 1), b2 = rlf(w2, j + 1);
                float b3 = rlf(w3, j + 1), b4 = rlf(w4, j + 1), b5 = rlf(w5, j + 1);
                d0 += b0; d1 += b1; d2 += b2; d3 += b3; d4 += b4; d5 += b5;
                a00 += b0 * cur1.x; a10 += b0 * cur1.y;
                a01 += b1 * cur1.x; a11 += b1 * cur1.y;
                a02 += b2 * cur1.x; a12 += b2 * cur1.y;
                a03 += b3 * cur1.x; a13 += b3 * cur1.y;
                a04 += b4 * cur1.x; a14 += b4 * cur1.y;
                a05 += b5 * cur1.x; a15 += b5 * cur1.y;
            }
            cur0 = nxt0; cur1 = nxt1;
            nxt0 = fut0; nxt1 = fut1;
        }
        float i0 = 1.f / d0, i1 = 1.f / d1, i2 = 1.f / d2;
        float i3 = 1.f / d3, i4 = 1.f / d4, i5 = 1.f / d5;
        int c = lane << 1;
        xsrow[0 * D + c] = (_Float16)(a00 * i0);  xsrow[0 * D + c + 1] = (_Float16)(a10 * i0);
        xsrow[1 * D + c] = (_Float16)(a01 * i1);  xsrow[1 * D + c + 1] = (_Float16)(a11 * i1);
        xsrow[2 * D + c] = (_Float16)(a02 * i2);  xsrow[2 * D + c + 1] = (_Float16)(a12 * i2);
        xsrow[3 * D + c] = (_Float16)(a03 * i3);  xsrow[3 * D + c + 1] = (_Float16)(a13 * i3);
        xsrow[4 * D + c] = (_Float16)(a04 * i4);  xsrow[4 * D + c + 1] = (_Float16)(a14 * i4);
        xsrow[5 * D + c] = (_Float16)(a05 * i5);  xsrow[5 * D + c + 1] = (_Float16)(a15 * i5);
    } else {
        // slow fallback (64 <= deg): single pass, no max-subtract.
        float adst[H];
        #pragma unroll
        for (int h = 0; h < H; h++) adst[h] = a[(size_t)n * 12 + 6 + h];
        int dl = deg < BSTRIDE ? deg : BSTRIDE;
        float d[H] = {0, 0, 0, 0, 0, 0};
        float acc0[H] = {0, 0, 0, 0, 0, 0};
        float acc1[H] = {0, 0, 0, 0, 0, 0};
        int c0 = lane, c1 = 64 + lane;
        for (int j = 0; j <= dl; j++) {
            int s = (j < dl) ? col[start + j] : n;
            float w[H];
            #pragma unroll
            for (int h = 0; h < H; h++) {
                float e = a[(size_t)s * 12 + h] + adst[h];
                e = (e > 0.f) ? e : 0.2f * e;
                w[h] = __expf(e);
                d[h] += w[h];
            }
            float xv0 = x[(size_t)s * D + c0];
            float xv1 = x[(size_t)s * D + c1];
            #pragma unroll
            for (int h = 0; h < H; h++) {
                acc0[h] += w[h] * xv0;
                acc1[h] += w[h] * xv1;
            }
        }
        #pragma unroll
        for (int h = 0; h < H; h++) {
            float inv = 1.0f / d[h];
            xsrow[h * D + c0] = (_Float16)(acc0[h] * inv);
            xsrow[h * D + c1] = (_Float16)(acc1[h] * inv);
        }
    }
}

// ---------------- fused layer: aggregate(8 nodes -> LDS) + MFMA GEMM + a ----------------
__global__ __launch_bounds__(512) void layer_kernel(const float* __restrict__ x,
                                                    const float* __restrict__ a_in,
                                                    const int* __restrict__ deg_,
                                                    const int* __restrict__ col,
                                                    const _Float16* __restrict__ bf,
                                                    const float* __restrict__ bias,
                                                    float* __restrict__ xout,
                                                    const _Float16* __restrict__ awf,
                                                    float* __restrict__ a_out, int M) {
    __shared__ _Float16 xs16[16][PADK];   // rows 0..7 aggregated; 8..15 garbage
    __shared__ _Float16 xso[16][136];     // output rows (f16) for fused a
    const int wave = (int)(threadIdx.x >> 6);
    const int lane = (int)(threadIdx.x & 63);
    const int m0 = (int)(blockIdx.x << 3);

    // phase 1: each wave aggregates 1 node
    {
        int n = m0 + wave;
        if (n < M)
            aggregate_node(x, a_in, deg_, col, n, lane, M, &xs16[wave][0]);
    }
    __syncthreads();

    // phase 2: GEMM — wave w owns col-tile w (cols w*16..w*16+15)
    f32x4 acc = {0.f, 0.f, 0.f, 0.f};
    const _Float16* ars = &xs16[lane & 15][(lane >> 4) << 3];
    const _Float16* bp = bf + (size_t)wave * 512 + (size_t)lane * 8;
    for (int t = 0; t < TSTEPS; t++) {
        f16x8 av = *(const f16x8*)(ars + t * 32);
        f16x8 bv = *(const f16x8*)(bp + (size_t)t * 4096);
        acc = __builtin_amdgcn_mfma_f32_16x16x32_f16(av, bv, acc, 0, 0, 0);
    }

    const float inv6 = 1.0f / 6.0f;
    const int cl = lane & 15;
    const int ccol = wave * 16 + cl;
    const int r0 = (lane >> 4) << 2;
    const float bs = bias[ccol];
    #pragma unroll
    for (int reg = 0; reg < 4; reg++) {
        int ml = r0 + reg;
        int m = m0 + ml;
        float v = acc[reg] * inv6 + bs;
        v = v > 0.f ? v : 0.f;
        if (ml < NPB && m < M) xout[(size_t)m * D + ccol] = v;
        xso[ml][ccol] = (_Float16)v;
    }

    // phase 3: fused next-layer attention logits (wave 0)
    if (awf) {
        __syncthreads();
        if (wave == 0) {
            f32x4 ac = {0.f, 0.f, 0.f, 0.f};
            #pragma unroll
            for (int t = 0; t < 4; t++) {
                f16x8 av = *(const f16x8*)&xso[cl][t * 32 + ((lane >> 4) << 3)];
                f16x8 bv = *(const f16x8*)(awf + (size_t)t * 512 + (size_t)lane * 8);
                ac = __builtin_amdgcn_mfma_f32_16x16x32_f16(av, bv, ac, 0, 0, 0);
            }
            if (cl < 12) {
                #pragma unroll
                for (int reg = 0; reg < 4; reg++) {
                    int ml = r0 + reg;
                    int m = m0 + ml;
                    if (ml < NPB && m < M) a_out[(size_t)m * 12 + cl] = ac[reg];
                }
            }
        }
    }
}

// ---------------- host ----------------

extern "C" void kernel_launch(void* const* d_in, const int* in_sizes, int n_in,
                              void* d_out, int out_size, void* d_ws, size_t ws_size,
                              hipStream_t stream) {
    const float* x_in = (const float*)d_in[0];
    const int* ei = (const int*)d_in[1];
    int N = in_sizes[0] / D;
    int E = in_sizes[1] / 2;
    const int* srcp = ei;
    const int* dstp = ei + E;

    size_t bf_halves_per_layer = (size_t)TSTEPS * 8 * 512;   // 98304

    float* ws = (float*)d_ws;
    float* bufA = ws;
    float* bufB = bufA + (size_t)N * D;
    float* abuf0 = bufB + (size_t)N * D;
    float* abuf1 = abuf0 + (size_t)N * 12;
    float* wa_all = abuf1 + (size_t)N * 12;          // 4*1536 floats
    _Float16* waf = (_Float16*)(wa_all + 4 * 1536);  // 4 layers x 2048 halves
    _Float16* w16f = waf + 4 * 2048;
    int* deg = (int*)(w16f + 4 * bf_halves_per_layer);
    int* col = deg + N;                               // N * BSTRIDE ints

    FoldArgs fa;
    for (int l = 0; l < 4; l++) {
        fa.W[l]  = (const float*)d_in[2 + 4 * l];
        fa.as[l] = (const float*)d_in[3 + 4 * l];
        fa.ad[l] = (const float*)d_in[4 + 4 * l];
    }

    // K1: zero deg + wa_all dots
    int n4 = (N + 3) / 4;
    int zBlocks = (n4 + 255) / 256;
    zero_wa_kernel<<<zBlocks + 24, 256, 0, stream>>>((int4*)deg, n4, zBlocks, fa, wa_all);

    // K2: scatter-hist | bf pack | waf pack | layer-0 a
    int scatBlocks = (E + 255) / 256;
    int a0Blocks = (N + 15) / 16;
    prep2_kernel<<<scatBlocks + 192 + 4 + a0Blocks, 256, 0, stream>>>(
        srcp, dstp, deg, col, E, scatBlocks, fa, wa_all, waf, w16f, x_in, abuf0, N);

    const float* xcur = x_in;
    float* acur = abuf0;
    float* anext = abuf1;
    for (int l = 0; l < 4; l++) {
        const float* b = (const float*)d_in[5 + 4 * l];
        float* xout = (l == 3) ? (float*)d_out : ((l & 1) ? bufB : bufA);
        const _Float16* awf = (l < 3) ? (waf + (size_t)(l + 1) * 2048) : (const _Float16*)nullptr;

        layer_kernel<<<(N + NPB - 1) / NPB, 512, 0, stream>>>(xcur, acur, deg, col,
                                                              w16f + (size_t)l * bf_halves_per_layer,
                                                              b, xout, awf, anext, N);
        xcur = xout;
        float* tmp = acur; acur = anext; anext = tmp;
    }
}